// Round 3
// baseline (252.468 us; speedup 1.0000x reference)
//
#include <hip/hip_runtime.h>
#include <cstdint>
#include <cstddef>

// Problem constants (match reference setup_inputs)
#define BB 32
#define SS 4096          // 2^12
#define FEAT_ 64
#define HID_ 32
#define NN 1024          // MAX_NODES
#define RPB 8            // adjacency rows per block (dense LDS tile = 32 KB)

#define EDGE_BLOCKS ((BB * SS) / 256)   // fallback path
#define NF_BLOCKS   ((BB * NN) / 32)

typedef int v4i __attribute__((ext_vector_type(4)));

// ---------------------------------------------------------------------------
// Shared device helper: edge weight from the factored MLP.
//   AB[n][0:32]  = emb[n] @ W1[0:64] + b1     (A half)
//   AB[n][32:64] = emb[n] @ W1[64:128]        (B half)
// Float expression kept IDENTICAL to the round-1 edge phase -> bit-identical w.
// ---------------------------------------------------------------------------
__device__ __forceinline__ float edge_weight(const float* __restrict__ ab,
                                             const float* __restrict__ W2,
                                             float b2v, int src_n, int dst_n,
                                             float volv) {
    const float4* As = (const float4*)(ab + (src_n << 6));
    const float4* Bd = (const float4*)(ab + (dst_n << 6) + HID_);
    float dotv = b2v;
    #pragma unroll
    for (int q = 0; q < 8; ++q) {
        float4 a  = As[q];
        float4 bv = Bd[q];
        float4 wv = *(const float4*)(W2 + (q << 2));
        dotv += fmaxf(a.x + bv.x, 0.0f) * wv.x;
        dotv += fmaxf(a.y + bv.y, 0.0f) * wv.y;
        dotv += fmaxf(a.z + bv.z, 0.0f) * wv.z;
        dotv += fmaxf(a.w + bv.w, 0.0f) * wv.w;
    }
    float edge_w = 1.0f / (1.0f + expf(-dotv));
    float vol_w  = 1.0f / (1.0f + expf(-volv / 1000.0f));
    return edge_w * vol_w;
}

// ---------------------------------------------------------------------------
// K1 (setup): grid-fused AB table + per-batch CSRs.
//   blocks [0,256)   : AB table (1024x64)
//   blocks [256,288) : dst-keyed CSR (other=src), buckets SORTED by s so the
//                      nf consumer accumulates in ascending-s order
//                      (bit-identical to the round-1 ballot-scan order)
//   blocks [288,320) : src-keyed CSR (other=dst), unsorted (adj uses explicit
//                      priorities, order-independent)
// CSR entry packs s(12b) | other(10b)<<12 | key_row(10b)<<22.
// ---------------------------------------------------------------------------
__global__ void setup_kernel(const float* __restrict__ emb,
                             const float* __restrict__ W1,
                             const float* __restrict__ b1,
                             const int* __restrict__ src,
                             const int* __restrict__ dst,
                             float* __restrict__ ab,
                             int* __restrict__ offD, int* __restrict__ idxD,
                             int* __restrict__ offS, int* __restrict__ idxS) {
    int t = threadIdx.x;
    if (blockIdx.x < 256) {
        int idx = blockIdx.x * 256 + t;                 // 0..65535
        int n = idx >> 6, c = idx & 63;
        int half = c >> 5, j = c & 31;
        const float* e = emb + (n << 6);                // wave-uniform row
        const float* w = W1 + (half << 11) + j;
        float acc = half ? 0.0f : b1[j];
        #pragma unroll
        for (int k = 0; k < 64; ++k) acc = fmaf(e[k], w[k << 5], acc);
        ab[idx] = acc;
        return;
    }

    int blk = blockIdx.x - 256;
    int dir = blk >> 5;                     // 0 = dst-CSR, 1 = src-CSR
    int b   = blk & 31;
    const int* keyg = (dir ? src : dst) + (size_t)b * SS;
    const int* othg = (dir ? dst : src) + (size_t)b * SS;
    int* offg = (dir ? offS : offD) + b * (NN + 1);
    int* idxg = (dir ? idxS : idxD) + b * SS;

    int kv[16], ov[16];
    #pragma unroll
    for (int i = 0; i < 16; ++i) {
        kv[i] = keyg[t + (i << 8)];
        ov[i] = othg[t + (i << 8)];
    }

    __shared__ int cnt[NN];
    __shared__ int wtot[4];
    #pragma unroll
    for (int i = 0; i < 4; ++i) cnt[(t << 2) + i] = 0;
    __syncthreads();
    #pragma unroll
    for (int i = 0; i < 16; ++i) atomicAdd(&cnt[kv[i]], 1);
    __syncthreads();

    // exclusive prefix scan of 1024 counts with 256 threads (4 counts each)
    int c0 = cnt[t * 4], c1 = cnt[t * 4 + 1], c2 = cnt[t * 4 + 2], c3 = cnt[t * 4 + 3];
    int p1 = c0 + c1, p2 = p1 + c2, p3 = p2 + c3;
    int x = p3;
    int lane = t & 63, wv = t >> 6;
    #pragma unroll
    for (int d = 1; d < 64; d <<= 1) {
        int y = __shfl_up(x, d, 64);
        if (lane >= d) x += y;
    }
    if (lane == 63) wtot[wv] = x;
    __syncthreads();
    int wbase = 0;
    #pragma unroll
    for (int w2 = 0; w2 < 4; ++w2) if (w2 < wv) wbase += wtot[w2];
    int e0 = wbase + x - p3;                 // exclusive offset of bucket 4t
    int e1 = e0 + c0, e2 = e0 + p1, e3 = e0 + p2;
    offg[t * 4 + 0] = e0; offg[t * 4 + 1] = e1;
    offg[t * 4 + 2] = e2; offg[t * 4 + 3] = e3;
    if (t == 255) offg[NN] = SS;
    __syncthreads();                         // scan reads of cnt[] done
    cnt[t * 4] = e0; cnt[t * 4 + 1] = e1; cnt[t * 4 + 2] = e2; cnt[t * 4 + 3] = e3;
    __syncthreads();

    #pragma unroll
    for (int i = 0; i < 16; ++i) {
        int s = t + (i << 8);
        int pos = atomicAdd(&cnt[kv[i]], 1);
        idxg[pos] = (int)((unsigned)s | ((unsigned)ov[i] << 12) | ((unsigned)kv[i] << 22));
    }

    if (dir == 0) {
        __syncthreads();                     // all scatter writes visible
        // per-bucket insertion sort by s (buckets avg 4 entries, L2-resident)
        int beg[4] = {e0, e1, e2, e3};
        int len[4] = {c0, c1, c2, c3};
        #pragma unroll
        for (int q = 0; q < 4; ++q) {
            int lo = beg[q], hi = beg[q] + len[q];
            for (int p = lo + 1; p < hi; ++p) {
                int v = idxg[p];
                int sq = v & 4095;
                int r = p - 1;
                while (r >= lo && (idxg[r] & 4095) > sq) { idxg[r + 1] = idxg[r]; --r; }
                idxg[r + 1] = v;
            }
        }
    }
}

// ---------------------------------------------------------------------------
// K2 (fused): 5120 blocks in groups of 5 = {4 adj, 1 nf} so flow reads
// overlap the adjacency nt-store drain.
//
// adj block (4096): dense 32 KB LDS priority tile, edge discovery via CSRs
// (~64 entries/block). Phase-2 winners compute w INLINE from the AB table.
//
// nf block (1024): pure CSR gather, ascending-s accumulation (bit-identical
// to the ballot-scan version), 4-wide load batching, butterfly L2-normalize,
// nt row stores. NOTE: r0 here is batch-LOCAL; global nf row = b*NN + r0 + j
// (the round-2 bug was using r0 directly).
// ---------------------------------------------------------------------------
__global__ void fused_kernel(const float* __restrict__ flow,
                             const float* __restrict__ vol,
                             const float* __restrict__ ab,
                             const float* __restrict__ W2,
                             const float* __restrict__ b2,
                             const int* __restrict__ offD, const int* __restrict__ idxD,
                             const int* __restrict__ offS, const int* __restrict__ idxS,
                             float* __restrict__ nf,
                             float* __restrict__ adj) {
    int g = blockIdx.x / 5;
    int r = blockIdx.x - g * 5;
    int t = threadIdx.x;
    __shared__ int D[RPB * NN];              // 32 KB (unused by nf blocks)

    if (r == 4) {
        // ---- node-features block: 32 rows (4 waves x 8 rows) ----
        int nb = g;                          // 0..1023
        int b = nb >> 5;
        int row0 = (nb & 31) << 5;           // batch-local first row
        int wave = t >> 6, lane = t & 63;
        int r0 = row0 + (wave << 3);         // batch-local
        const float* fb = flow + ((size_t)b * SS << 6);
        const int* offb = offD + b * (NN + 1);
        const int* idxb = idxD + b * SS;
        #pragma unroll
        for (int j = 0; j < 8; ++j) {
            int row = r0 + j;                // batch-local node id
            int eb = offb[row], ee = offb[row + 1];
            float a = 0.f;
            int e = eb;
            for (; e + 4 <= ee; e += 4) {    // batch 4 loads, keep s-order adds
                int s0 = idxb[e]     & 4095, s1 = idxb[e + 1] & 4095;
                int s2 = idxb[e + 2] & 4095, s3 = idxb[e + 3] & 4095;
                float v0 = fb[(s0 << 6) + lane], v1 = fb[(s1 << 6) + lane];
                float v2 = fb[(s2 << 6) + lane], v3 = fb[(s3 << 6) + lane];
                a = (((a + v0) + v1) + v2) + v3;
            }
            for (; e < ee; ++e) {
                int s = idxb[e] & 4095;
                a += fb[(s << 6) + lane];
            }
            float ssum = a * a;
            #pragma unroll
            for (int off = 32; off > 0; off >>= 1) ssum += __shfl_xor(ssum, off, 64);
            float v = a / fmaxf(sqrtf(ssum), 1e-12f);
            __builtin_nontemporal_store(
                v, &nf[((size_t)(b * NN + row) << 6) + lane]);   // GLOBAL row
        }
        return;
    }

    // ---- adjacency block ----
    int aidx = g * 4 + r;                    // 0..4095
    int b  = aidx >> 7;
    int r0 = (aidx & 127) << 3;

    const int* offSb = offS + b * (NN + 1);
    const int* offDb = offD + b * (NN + 1);
    const int* idxSb = idxS + b * SS;
    const int* idxDb = idxD + b * SS;
    int begS = offSb[r0], cntS = offSb[r0 + RPB] - begS;
    int begD = offDb[r0], cntD = offDb[r0 + RPB] - begD;

    int4* D4 = (int4*)D;
    int4 z; z.x = z.y = z.z = z.w = 0;
    #pragma unroll
    for (int i = 0; i < RPB * NN / 4 / 256; ++i) D4[t + i * 256] = z;
    __syncthreads();

    // phase 1: priority max. prio ranges disjoint & unique -> max == numpy
    // last-write-wins (pass-2 (dst,src) writes always beat pass-1).
    for (int i = t; i < cntS; i += 256) {
        unsigned v = (unsigned)idxSb[begS + i];
        int s = (int)(v & 4095u); int col = (int)((v >> 12) & 1023u); int row = (int)(v >> 22);
        atomicMax(&D[((row - r0) << 10) + col], s + 1);
    }
    for (int i = t; i < cntD; i += 256) {
        unsigned v = (unsigned)idxDb[begD + i];
        int s = (int)(v & 4095u); int col = (int)((v >> 12) & 1023u); int row = (int)(v >> 22);
        atomicMax(&D[((row - r0) << 10) + col], SS + s + 1);
    }
    __syncthreads();

    // phase 2: unique winner per cell computes w inline and deposits bits.
    const float* volb = vol + (size_t)b * SS;
    float b2v = b2[0];
    for (int i = t; i < cntS; i += 256) {
        unsigned v = (unsigned)idxSb[begS + i];
        int s = (int)(v & 4095u); int col = (int)((v >> 12) & 1023u); int row = (int)(v >> 22);
        int cell = ((row - r0) << 10) + col;
        if (D[cell] == s + 1)                // src-keyed: src=row, dst=col
            D[cell] = __float_as_int(edge_weight(ab, W2, b2v, row, col, volb[s]));
    }
    for (int i = t; i < cntD; i += 256) {
        unsigned v = (unsigned)idxDb[begD + i];
        int s = (int)(v & 4095u); int col = (int)((v >> 12) & 1023u); int row = (int)(v >> 22);
        int cell = ((row - r0) << 10) + col;
        if (D[cell] == SS + s + 1)           // dst-keyed: dst=row, src=col
            D[cell] = __float_as_int(edge_weight(ab, W2, b2v, col, row, volb[s]));
    }
    __syncthreads();

    // phase 3: stream 8 full rows out, nt float4 (bypass L2 write-allocate)
    const v4i* Df = (const v4i*)D;
    v4i* out = (v4i*)(adj + ((size_t)b * NN + r0) * NN);
    #pragma unroll
    for (int i = 0; i < RPB * NN / 4 / 256; ++i)
        __builtin_nontemporal_store(Df[t + i * 256], &out[t + i * 256]);
}

// ===========================================================================
// Fallback path (round-1 proven kernels) — used only if ws_size is too small
// for the CSR workspace.
// ===========================================================================
__global__ void ab_kernel(const float* __restrict__ emb,
                          const float* __restrict__ W1,
                          const float* __restrict__ b1,
                          float* __restrict__ ab) {
    int idx = blockIdx.x * 256 + threadIdx.x;
    int n = idx >> 6, c = idx & 63;
    int half = c >> 5, j = c & 31;
    const float* e = emb + (n << 6);
    const float* w = W1 + (half << 11) + j;
    float acc = half ? 0.0f : b1[j];
    #pragma unroll
    for (int k = 0; k < 64; ++k) acc = fmaf(e[k], w[k << 5], acc);
    ab[idx] = acc;
}

__global__ void nf_edge_kernel(const float* __restrict__ flow,
                               const int* __restrict__ src,
                               const int* __restrict__ dst,
                               const float* __restrict__ vol,
                               const float* __restrict__ ab,
                               const float* __restrict__ W2,
                               const float* __restrict__ b2,
                               float* __restrict__ nf,
                               float* __restrict__ wout) {
    if (blockIdx.x < EDGE_BLOCKS) {
        int i = blockIdx.x * 256 + threadIdx.x;
        int si = src[i], di = dst[i];
        float w = edge_weight(ab, W2, b2[0], si, di, vol[i]);
        wout[i] = w;
        return;
    }
    int nb = blockIdx.x - EDGE_BLOCKS;
    int row0 = nb << 5;
    int b = row0 >> 10;
    __shared__ int sdst[SS];
    const int4* g = (const int4*)(dst + (size_t)b * SS);
    int4* sd4 = (int4*)sdst;
    for (int t = threadIdx.x; t < SS / 4; t += 256) sd4[t] = g[t];
    __syncthreads();
    int wave = threadIdx.x >> 6, lane = threadIdx.x & 63;
    int r0 = row0 + (wave << 3);
    int node0 = r0 & (NN - 1);
    const float* fb = flow + ((size_t)b * SS << 6);
    float acc[8] = {0.f,0.f,0.f,0.f,0.f,0.f,0.f,0.f};
    for (int s0 = 0; s0 < SS; s0 += 64) {
        int d = sdst[s0 + lane];
        #pragma unroll
        for (int j = 0; j < 8; ++j) {
            unsigned long long m = __ballot(d == node0 + j);
            while (m) {
                int bit = __ffsll((long long)m) - 1;
                m &= m - 1;
                acc[j] += fb[((s0 + bit) << 6) + lane];
            }
        }
    }
    #pragma unroll
    for (int j = 0; j < 8; ++j) {
        float ss = acc[j] * acc[j];
        #pragma unroll
        for (int off = 32; off > 0; off >>= 1) ss += __shfl_xor(ss, off, 64);
        float v = acc[j] / fmaxf(sqrtf(ss), 1e-12f);
        __builtin_nontemporal_store(v, &nf[((size_t)(r0 + j) << 6) + lane]);
    }
}

__global__ void adj_dense_kernel(const int* __restrict__ src,
                                 const int* __restrict__ dst,
                                 const float* __restrict__ wbuf,
                                 float* __restrict__ adj) {
    int b  = blockIdx.x >> 7;
    int r0 = (blockIdx.x & 127) << 3;
    int tid = threadIdx.x;
    __shared__ int D[RPB * NN];
    const int* sb = src + (size_t)b * SS;
    const int* db = dst + (size_t)b * SS;
    int svr[16], dvr[16];
    #pragma unroll
    for (int i = 0; i < 16; ++i) { svr[i] = sb[tid + (i << 8)]; dvr[i] = db[tid + (i << 8)]; }
    int4* D4 = (int4*)D;
    int4 z; z.x = z.y = z.z = z.w = 0;
    #pragma unroll
    for (int i = 0; i < RPB * NN / 4 / 256; ++i) D4[tid + i * 256] = z;
    __syncthreads();
    #pragma unroll
    for (int i = 0; i < 16; ++i) {
        int s = tid + (i << 8);
        unsigned lr1 = (unsigned)(svr[i] - r0);
        if (lr1 < RPB) atomicMax(&D[(lr1 << 10) + dvr[i]], s + 1);
        unsigned lr2 = (unsigned)(dvr[i] - r0);
        if (lr2 < RPB) atomicMax(&D[(lr2 << 10) + svr[i]], SS + s + 1);
    }
    __syncthreads();
    const float* wb = wbuf + (size_t)b * SS;
    #pragma unroll
    for (int i = 0; i < 16; ++i) {
        int s = tid + (i << 8);
        unsigned lr1 = (unsigned)(svr[i] - r0);
        unsigned lr2 = (unsigned)(dvr[i] - r0);
        if ((lr1 < RPB) | (lr2 < RPB)) {
            int wbits = __float_as_int(wb[s]);
            if (lr1 < RPB && D[(lr1 << 10) + dvr[i]] == s + 1) D[(lr1 << 10) + dvr[i]] = wbits;
            if (lr2 < RPB && D[(lr2 << 10) + svr[i]] == SS + s + 1) D[(lr2 << 10) + svr[i]] = wbits;
        }
    }
    __syncthreads();
    const v4i* Df = (const v4i*)D;
    v4i* out = (v4i*)(adj + ((size_t)b * NN + r0) * NN);
    #pragma unroll
    for (int i = 0; i < RPB * NN / 4 / 256; ++i)
        __builtin_nontemporal_store(Df[tid + i * 256], &out[tid + i * 256]);
}

extern "C" void kernel_launch(void* const* d_in, const int* in_sizes, int n_in,
                              void* d_out, int out_size, void* d_ws, size_t ws_size,
                              hipStream_t stream) {
    const float* flow = (const float*)d_in[0];   // (B,S,64)
    const int*   src  = (const int*)d_in[1];     // (B,S)
    const int*   dst  = (const int*)d_in[2];     // (B,S)
    const float* vol  = (const float*)d_in[3];   // (B,S)
    const float* emb  = (const float*)d_in[4];   // (1024,64)
    const float* W1   = (const float*)d_in[5];   // (128,32)
    const float* b1   = (const float*)d_in[6];   // (32,)
    const float* W2   = (const float*)d_in[7];   // (32,1)
    const float* b2   = (const float*)d_in[8];   // (1,)

    float* nf  = (float*)d_out;                         // (B,N,64)
    float* adj = nf + (size_t)BB * NN * FEAT_;          // (B,N,N)

    // CSR-path workspace: ab(256KB) + offD + idxD + offS + idxS ≈ 1.6 MB
    size_t need = ((size_t)NN * 64 + 2 * (size_t)BB * (NN + 1) + 2 * (size_t)BB * SS)
                  * sizeof(float);
    if (ws_size >= need) {
        float* ab  = (float*)d_ws;
        int* offD = (int*)(ab + NN * 64);
        int* idxD = offD + BB * (NN + 1);
        int* offS = idxD + BB * SS;
        int* idxS = offS + BB * (NN + 1);
        setup_kernel<<<320, 256, 0, stream>>>(emb, W1, b1, src, dst,
                                              ab, offD, idxD, offS, idxS);
        fused_kernel<<<5120, 256, 0, stream>>>(flow, vol, ab, W2, b2,
                                               offD, idxD, offS, idxS, nf, adj);
        return;
    }

    // fallback: round-1 proven 3-kernel path
    float* wbuf = (float*)d_ws;                         // (B,S)
    float* ab;
    if (ws_size >= (size_t)(BB * SS + NN * 64) * sizeof(float))
        ab = wbuf + (size_t)BB * SS;
    else
        ab = adj + (size_t)BB * NN * NN - (size_t)NN * 64;
    ab_kernel<<<(NN * 64) / 256, 256, 0, stream>>>(emb, W1, b1, ab);
    nf_edge_kernel<<<EDGE_BLOCKS + NF_BLOCKS, 256, 0, stream>>>(
        flow, src, dst, vol, ab, W2, b2, nf, wbuf);
    adj_dense_kernel<<<BB * (NN / RPB), 256, 0, stream>>>(src, dst, wbuf, adj);
}